// Round 3
// baseline (272.045 us; speedup 1.0000x reference)
//
#include <hip/hip_runtime.h>
#include <math.h>

#define D_MODELc 1024
#define N_HEADSc 16
#define D_Kc     64
#define B_SZc    2
#define S_LENc   2048
#define NTOKc    (B_SZc * S_LENc)   // 4096

using half8  = __attribute__((ext_vector_type(8))) _Float16;
using half4  = __attribute__((ext_vector_type(4))) _Float16;
using fp16x2 = __attribute__((ext_vector_type(2))) __fp16;
using float4v = __attribute__((ext_vector_type(4))) float;

// ---------------------------------------------------------------------------
// Fused convert: z<4 -> weight fp32->fp16 transpose; z==4 -> x fp32->fp16.
// ---------------------------------------------------------------------------
__global__ __launch_bounds__(256) void cvt_all(
    const float* __restrict__ x,
    const float* __restrict__ W0, const float* __restrict__ W1,
    const float* __restrict__ W2, const float* __restrict__ W3,
    _Float16* __restrict__ wout, _Float16* __restrict__ xout)
{
    __shared__ float T[32][33];
    const int z = blockIdx.z;
    const int t = threadIdx.x;

    if (z == 4) {   // x convert: 1024 virtual blocks x 512 half8
        const int bid = blockIdx.y * 32 + blockIdx.x;
        #pragma unroll
        for (int c = 0; c < 2; ++c) {
            const int i = bid * 512 + c * 256 + t;
            float4v a = ((const float4v*)x)[2 * i];
            float4v b = ((const float4v*)x)[2 * i + 1];
            half8 h;
            h[0] = (_Float16)a[0]; h[1] = (_Float16)a[1];
            h[2] = (_Float16)a[2]; h[3] = (_Float16)a[3];
            h[4] = (_Float16)b[0]; h[5] = (_Float16)b[1];
            h[6] = (_Float16)b[2]; h[7] = (_Float16)b[3];
            ((half8*)xout)[i] = h;
        }
        return;
    }

    const float* W = (z == 0) ? W0 : (z == 1) ? W1 : (z == 2) ? W2 : W3;
    _Float16* O = wout + (size_t)z * 1024 * 1024;

    const int k0 = blockIdx.x * 32;
    const int n0 = blockIdx.y * 32;
    {
        const int r = t >> 3, c4 = (t & 7) * 4;
        float4v v = *(const float4v*)(W + (size_t)(k0 + r) * 1024 + n0 + c4);
        T[r][c4 + 0] = v[0]; T[r][c4 + 1] = v[1];
        T[r][c4 + 2] = v[2]; T[r][c4 + 3] = v[3];
    }
    __syncthreads();
    {
        const int rn = t >> 3, ck4 = (t & 7) * 4;
        half4 h;
        h[0] = (_Float16)T[ck4 + 0][rn];
        h[1] = (_Float16)T[ck4 + 1][rn];
        h[2] = (_Float16)T[ck4 + 2][rn];
        h[3] = (_Float16)T[ck4 + 3][rn];
        *(half4*)(O + (size_t)(n0 + rn) * 1024 + k0 + ck4) = h;
    }
}

// ---------------------------------------------------------------------------
// QKV fp16 MFMA GEMM: 128x128 tiles, BK=64 via dual 32-k buffers.
// fp16 out, z-indexed: z==0 Q scaled by 0.125/ln2; z==1 K; z==2 V transposed.
// ---------------------------------------------------------------------------
__global__ __launch_bounds__(256) void gemm_qkv(
    const _Float16* __restrict__ A, const _Float16* __restrict__ BtAll,
    const float* __restrict__ bias0, const float* __restrict__ bias1,
    const float* __restrict__ bias2, _Float16* __restrict__ Cout)
{
    __shared__ _Float16 Als[2][128 * 32];
    __shared__ _Float16 Bls[2][128 * 32];

    constexpr int K = 1024;
    const int tid = threadIdx.x;
    const int m0  = blockIdx.x * 128;
    const int n0  = blockIdx.y * 128;
    const int z   = blockIdx.z;

    const _Float16* Bt  = BtAll + (size_t)z * 1024 * 1024;
    const float* bias   = (z == 0) ? bias0 : (z == 1) ? bias1 : bias2;
    const float qscale  = (z == 0) ? 0.18033688011112042f : 1.0f;

    const int wave = tid >> 6, lane = tid & 63;
    const int wr = wave >> 1, wc = wave & 1;
    const int quad = lane >> 4, l16 = lane & 15;

    float4v acc[4][4];
    #pragma unroll
    for (int i = 0; i < 4; ++i)
        #pragma unroll
        for (int j = 0; j < 4; ++j)
            acc[i][j] = (float4v){0.f, 0.f, 0.f, 0.f};

    for (int k0 = 0; k0 < K; k0 += 64) {
        #pragma unroll
        for (int c = 0; c < 2; ++c) {
            const int i   = c * 256 + tid;
            const int row = i >> 2, kc = i & 3;
            #pragma unroll
            for (int h = 0; h < 2; ++h) {
                __builtin_amdgcn_global_load_lds(
                    (const __attribute__((address_space(1))) void*)
                        (A + (size_t)(m0 + row) * K + k0 + h * 32 + kc * 8),
                    (__attribute__((address_space(3))) void*)(Als[h] + i * 8),
                    16, 0, 0);
                __builtin_amdgcn_global_load_lds(
                    (const __attribute__((address_space(1))) void*)
                        (Bt + (size_t)(n0 + row) * K + k0 + h * 32 + kc * 8),
                    (__attribute__((address_space(3))) void*)(Bls[h] + i * 8),
                    16, 0, 0);
            }
        }
        __syncthreads();

        half8 af[4][2], bf[4][2];
        #pragma unroll
        for (int i = 0; i < 4; ++i) {
            const int r = (wr * 64 + i * 16 + l16) * 32 + quad * 8;
            af[i][0] = *(const half8*)(Als[0] + r);
            af[i][1] = *(const half8*)(Als[1] + r);
        }
        #pragma unroll
        for (int j = 0; j < 4; ++j) {
            const int r = (wc * 64 + j * 16 + l16) * 32 + quad * 8;
            bf[j][0] = *(const half8*)(Bls[0] + r);
            bf[j][1] = *(const half8*)(Bls[1] + r);
        }
        #pragma unroll
        for (int i = 0; i < 4; ++i)
            #pragma unroll
            for (int j = 0; j < 4; ++j) {
                acc[i][j] = __builtin_amdgcn_mfma_f32_16x16x32_f16(
                    af[i][0], bf[j][0], acc[i][j], 0, 0, 0);
                acc[i][j] = __builtin_amdgcn_mfma_f32_16x16x32_f16(
                    af[i][1], bf[j][1], acc[i][j], 0, 0, 0);
            }
        __syncthreads();
    }

    if (z != 2) {
        // Q/K: [b,h,s,dk] scatter (fp16)
        #pragma unroll
        for (int i = 0; i < 4; ++i) {
            const int rbase = m0 + wr * 64 + i * 16 + quad * 4;
            #pragma unroll
            for (int j = 0; j < 4; ++j) {
                const int col = n0 + wc * 64 + j * 16 + l16;
                const float bv = bias[col];
                #pragma unroll
                for (int r = 0; r < 4; ++r) {
                    const float v = (acc[i][j][r] + bv) * qscale;
                    const int n = rbase + r;
                    const int b = n >> 11, s = n & 2047;
                    const int h = col >> 6, d = col & 63;
                    _Float16* C = Cout + (size_t)z * NTOKc * D_MODELc;
                    C[(((size_t)(b * N_HEADSc + h)) * S_LENc + s) * D_Kc + d] =
                        (_Float16)v;
                }
            }
        }
    } else {
        // V: [b,h,dk,s], half4 packed along tokens
        #pragma unroll
        for (int i = 0; i < 4; ++i) {
            const int rbase = m0 + wr * 64 + i * 16 + quad * 4;
            const int b = rbase >> 11, s0 = rbase & 2047;
            #pragma unroll
            for (int j = 0; j < 4; ++j) {
                const int col = n0 + wc * 64 + j * 16 + l16;
                const float bv = bias[col];
                const int h = col >> 6, d = col & 63;
                half4 hv;
                #pragma unroll
                for (int r = 0; r < 4; ++r)
                    hv[r] = (_Float16)(acc[i][j][r] + bv);
                _Float16* C = Cout + (size_t)2 * NTOKc * D_MODELc;
                *(half4*)(C + (((size_t)(b * N_HEADSc + h)) * D_Kc + d) *
                          S_LENc + s0) = hv;
            }
        }
    }
}

// ---------------------------------------------------------------------------
// Out-projection GEMM: C[4096,1024] fp32 = A @ Bt^T + bias.
// ---------------------------------------------------------------------------
__global__ __launch_bounds__(256) void gemm_out(
    const _Float16* __restrict__ A, const _Float16* __restrict__ Bt,
    const float* __restrict__ bias, float* __restrict__ C)
{
    __shared__ _Float16 Als[2][64 * 32];
    __shared__ _Float16 Bls[2][128 * 32];

    constexpr int K = 1024;
    const int tid = threadIdx.x;
    const int m0  = blockIdx.x * 64;
    const int n0  = blockIdx.y * 128;

    const int wave = tid >> 6, lane = tid & 63;
    const int wr = wave >> 1, wc = wave & 1;
    const int quad = lane >> 4, l16 = lane & 15;

    float4v acc[2][4];
    #pragma unroll
    for (int i = 0; i < 2; ++i)
        #pragma unroll
        for (int j = 0; j < 4; ++j)
            acc[i][j] = (float4v){0.f, 0.f, 0.f, 0.f};

    for (int k0 = 0; k0 < K; k0 += 64) {
        {   // A: 64 rows x 32 k per buffer
            const int row = tid >> 2, kc = tid & 3;
            #pragma unroll
            for (int h = 0; h < 2; ++h)
                __builtin_amdgcn_global_load_lds(
                    (const __attribute__((address_space(1))) void*)
                        (A + (size_t)(m0 + row) * K + k0 + h * 32 + kc * 8),
                    (__attribute__((address_space(3))) void*)(Als[h] + tid * 8),
                    16, 0, 0);
        }
        #pragma unroll
        for (int c = 0; c < 2; ++c) {   // B: 128 rows x 32 k per buffer
            const int i = c * 256 + tid;
            const int row = i >> 2, kc = i & 3;
            #pragma unroll
            for (int h = 0; h < 2; ++h)
                __builtin_amdgcn_global_load_lds(
                    (const __attribute__((address_space(1))) void*)
                        (Bt + (size_t)(n0 + row) * K + k0 + h * 32 + kc * 8),
                    (__attribute__((address_space(3))) void*)(Bls[h] + i * 8),
                    16, 0, 0);
        }
        __syncthreads();

        half8 af[2][2], bf[4][2];
        #pragma unroll
        for (int i = 0; i < 2; ++i) {
            const int r = (wr * 32 + i * 16 + l16) * 32 + quad * 8;
            af[i][0] = *(const half8*)(Als[0] + r);
            af[i][1] = *(const half8*)(Als[1] + r);
        }
        #pragma unroll
        for (int j = 0; j < 4; ++j) {
            const int r = (wc * 64 + j * 16 + l16) * 32 + quad * 8;
            bf[j][0] = *(const half8*)(Bls[0] + r);
            bf[j][1] = *(const half8*)(Bls[1] + r);
        }
        #pragma unroll
        for (int i = 0; i < 2; ++i)
            #pragma unroll
            for (int j = 0; j < 4; ++j) {
                acc[i][j] = __builtin_amdgcn_mfma_f32_16x16x32_f16(
                    af[i][0], bf[j][0], acc[i][j], 0, 0, 0);
                acc[i][j] = __builtin_amdgcn_mfma_f32_16x16x32_f16(
                    af[i][1], bf[j][1], acc[i][j], 0, 0, 0);
            }
        __syncthreads();
    }

    #pragma unroll
    for (int i = 0; i < 2; ++i) {
        const int rbase = m0 + wr * 32 + i * 16 + quad * 4;
        #pragma unroll
        for (int j = 0; j < 4; ++j) {
            const int col = n0 + wc * 64 + j * 16 + l16;
            const float bv = bias[col];
            #pragma unroll
            for (int r = 0; r < 4; ++r)
                C[(size_t)(rbase + r) * 1024 + col] = acc[i][j][r] + bv;
        }
    }
}

// ---------------------------------------------------------------------------
// MFMA flash attention, S^T form, NO-MAX softmax, SPLIT-K over keys (SP=2).
// R10: NO K/V LDS STAGING. K/V per (bh,split) is 128KB each -> L2-resident;
// the 4 waves of a block read the same 8KB tile -> L1 serves intra-block
// reuse (m169 precedent: dropping cache-fit V-staging was +26%). kf/bvv
// fragments load DIRECTLY from global; Ks/Vt LDS and BOTH per-tile barriers
// deleted. Loop is now synchronization-free; compiler pipelines across
// iterations. Ps stays in LDS (PS=72 linear pad — R7's proven-cheap config;
// swizzle rejected in R8/R9: it breaks ds offset-imm folding, +16 VGPR and
// extra VALU on the critical pipe). Wave-private Ps rows -> no barrier.
// __launch_bounds__(256,4) caps VGPR at 128 so pipelining can't drop a
// wave slot. Partials additive: Opart=sum P*V, Lpart=sum p.
// ---------------------------------------------------------------------------
__global__ __launch_bounds__(256, 4) void attn_mfma(
    const _Float16* __restrict__ Qb, const _Float16* __restrict__ Kb,
    const _Float16* __restrict__ Vtg, _Float16* __restrict__ Op,
    float* __restrict__ Lp)
{
    constexpr int PS = 72;                 // padded LDS row stride (halves)
    __shared__ _Float16 Ps[128 * PS];      // P [qrow 0..127][key]  (18.4KB)

    const int tid  = threadIdx.x;
    const int wv   = tid >> 6;
    const int lane = tid & 63;
    const int quad = lane >> 4;
    const int l16  = lane & 15;

    const int q0 = blockIdx.x * 128;
    const int bh = blockIdx.y;
    const int sp = blockIdx.z;             // key split
    const int kb = sp * (S_LENc / 2);
    const int kend = kb + S_LENc / 2;

    const _Float16* Qsl = Qb  + (size_t)bh * S_LENc * D_Kc;
    const _Float16* Ksl = Kb  + (size_t)bh * S_LENc * D_Kc;
    const _Float16* Vsl = Vtg + (size_t)bh * S_LENc * D_Kc;   // [dk][s]

    // Q B-operand frags: lane l16 = qrow
    half8 aq[2][2];
    #pragma unroll
    for (int qf = 0; qf < 2; ++qf) {
        const int row = q0 + wv * 32 + qf * 16 + l16;
        aq[qf][0] = *(const half8*)(Qsl + (size_t)row * 64 + quad * 8);
        aq[qf][1] = *(const half8*)(Qsl + (size_t)row * 64 + 32 + quad * 8);
    }

    float4v O[2][4];                   // [qf][dk-tile]; qrow=quad*4+r, dk=nt*16+l16
    #pragma unroll
    for (int qf = 0; qf < 2; ++qf)
        #pragma unroll
        for (int nt = 0; nt < 4; ++nt)
            O[qf][nt] = (float4v){0.f, 0.f, 0.f, 0.f};
    float lr[2] = {0.f, 0.f};          // per-lane partial sum (qrow = l16)

    for (int t0 = kb; t0 < kend; t0 += 64) {
        // K fragments straight from global (L1/L2-hit; tile shared by 4 waves)
        half8 kf[4][2];
        #pragma unroll
        for (int nt = 0; nt < 4; ++nt) {
            const _Float16* kp =
                Ksl + (size_t)(t0 + nt * 16 + l16) * 64 + quad * 8;
            kf[nt][0] = *(const half8*)(kp);
            kf[nt][1] = *(const half8*)(kp + 32);
        }

        #pragma unroll
        for (int qf = 0; qf < 2; ++qf) {
            float4v st[4];
            #pragma unroll
            for (int nt = 0; nt < 4; ++nt) {
                st[nt] = __builtin_amdgcn_mfma_f32_16x16x32_f16(
                    kf[nt][0], aq[qf][0], (float4v){0.f, 0.f, 0.f, 0.f}, 0, 0, 0);
                st[nt] = __builtin_amdgcn_mfma_f32_16x16x32_f16(
                    kf[nt][1], aq[qf][1], st[nt], 0, 0, 0);
            }
            float ls = 0.f;
            const int rowP = (wv * 32 + qf * 16 + l16) * PS;
            #pragma unroll
            for (int nt = 0; nt < 4; ++nt) {
                const float p0 = __builtin_amdgcn_exp2f(fminf(st[nt][0], 15.5f));
                const float p1 = __builtin_amdgcn_exp2f(fminf(st[nt][1], 15.5f));
                const float p2 = __builtin_amdgcn_exp2f(fminf(st[nt][2], 15.5f));
                const float p3 = __builtin_amdgcn_exp2f(fminf(st[nt][3], 15.5f));
                ls += (p0 + p1) + (p2 + p3);
                union { fp16x2 h2[2]; half4 h4; } u;
                u.h2[0] = __builtin_amdgcn_cvt_pkrtz(p0, p1);
                u.h2[1] = __builtin_amdgcn_cvt_pkrtz(p2, p3);
                *(half4*)(Ps + rowP + nt * 16 + quad * 4) = u.h4;
            }
            lr[qf] += ls;
        }

        // V fragments straight from global ([dk][s] layout)
        half8 bvv[4][2];
        #pragma unroll
        for (int nt = 0; nt < 4; ++nt) {
            const _Float16* vp =
                Vsl + (size_t)(nt * 16 + l16) * S_LENc + t0 + quad * 8;
            bvv[nt][0] = *(const half8*)(vp);
            bvv[nt][1] = *(const half8*)(vp + 32);
        }
        #pragma unroll
        for (int qf = 0; qf < 2; ++qf) {
            const int rowP = (wv * 32 + qf * 16 + l16) * PS;
            half8 ap0 = *(const half8*)(Ps + rowP + quad * 8);
            half8 ap1 = *(const half8*)(Ps + rowP + 32 + quad * 8);
            #pragma unroll
            for (int nt = 0; nt < 4; ++nt) {
                O[qf][nt] = __builtin_amdgcn_mfma_f32_16x16x32_f16(
                    ap0, bvv[nt][0], O[qf][nt], 0, 0, 0);
                O[qf][nt] = __builtin_amdgcn_mfma_f32_16x16x32_f16(
                    ap1, bvv[nt][1], O[qf][nt], 0, 0, 0);
            }
        }
    }

    // epilogue: write unnormalized partials
    const size_t qgb = (size_t)bh * S_LENc;
    #pragma unroll
    for (int qf = 0; qf < 2; ++qf) {
        float t = lr[qf];
        t += __shfl_xor(t, 16, 64);
        t += __shfl_xor(t, 32, 64);
        if (quad == 0)
            Lp[(size_t)sp * 65536 + qgb + q0 + wv * 32 + qf * 16 + l16] = t;
        #pragma unroll
        for (int r = 0; r < 4; ++r) {
            const int q = q0 + wv * 32 + qf * 16 + quad * 4 + r;
            _Float16* dst = Op + ((size_t)sp * 65536 + qgb + q) * 64;
            #pragma unroll
            for (int nt = 0; nt < 4; ++nt)
                dst[nt * 16 + l16] = (_Float16)O[qf][nt][r];
        }
    }
}

// ---------------------------------------------------------------------------
// Combine split-K partials: Ah[b][s][h*64+d] = (O0+O1) / (l0+l1).
// ---------------------------------------------------------------------------
__global__ __launch_bounds__(256) void attn_combine(
    const _Float16* __restrict__ Op, const float* __restrict__ Lp,
    _Float16* __restrict__ Ab)
{
    const int i  = blockIdx.x * 256 + threadIdx.x;
    const int e0 = i * 8;
    const int qg = e0 >> 6;            // bh*2048 + q
    const int d0 = e0 & 63;
    const int bh = qg >> 11, q = qg & 2047;
    const int b  = bh >> 4,  h = bh & 15;

    const float inv = 1.0f / (Lp[qg] + Lp[65536 + qg]);
    half8 o0 = *(const half8*)(Op + (size_t)qg * 64 + d0);
    half8 o1 = *(const half8*)(Op + ((size_t)65536 + qg) * 64 + d0);
    half8 hv;
    #pragma unroll
    for (int j = 0; j < 8; ++j)
        hv[j] = (_Float16)(((float)o0[j] + (float)o1[j]) * inv);
    *(half8*)(Ab + ((size_t)(b * S_LENc + q)) * 1024 + h * 64 + d0) = hv;
}

// ---------------------------------------------------------------------------
extern "C" void kernel_launch(void* const* d_in, const int* in_sizes, int n_in,
                              void* d_out, int out_size, void* d_ws, size_t ws_size,
                              hipStream_t stream)
{
    const float* x  = (const float*)d_in[0];
    const float* wq = (const float*)d_in[1];
    const float* bq = (const float*)d_in[2];
    const float* wk = (const float*)d_in[3];
    const float* bk = (const float*)d_in[4];
    const float* wv = (const float*)d_in[5];
    const float* bv = (const float*)d_in[6];
    const float* wo = (const float*)d_in[7];
    const float* bo = (const float*)d_in[8];
    float* out = (float*)d_out;

    const size_t M1 = 1024 * 1024;
    const size_t M4 = 4 * M1;                 // 4.19M elements
    _Float16* xh = (_Float16*)d_ws;           // [0, 8.4MB)  also reused as Ah
    _Float16* wh = xh + M4;                   // 4 x 1M halves
    _Float16* Qh = wh + M4;                   // Q,K,V: 3 x 4M halves
    _Float16* Oph = Qh + 3 * M4;              // split partials: 2 x 4M halves
    float*    Lp  = (float*)(Oph + 2 * M4);   // 2 x 65536 floats
    _Float16* Ah = xh;                        // xh dead after QKV gemm

    cvt_all<<<dim3(32, 32, 5), dim3(256), 0, stream>>>(
        x, wq, wk, wv, wo, wh, xh);
    gemm_qkv<<<dim3(NTOKc / 128, D_MODELc / 128, 3), dim3(256), 0, stream>>>(
        xh, wh, bq, bk, bv, Qh);
    attn_mfma<<<dim3(S_LENc / 128, B_SZc * N_HEADSc, 2), dim3(256), 0, stream>>>(
        Qh, Qh + M4, Qh + 2 * M4, Oph, Lp);
    attn_combine<<<dim3(NTOKc * D_MODELc / 8 / 256), dim3(256), 0, stream>>>(
        Oph, Lp, Ah);
    gemm_out<<<dim3(NTOKc / 64, D_MODELc / 128), dim3(256), 0, stream>>>(
        Ah, wh + 3 * M1, bo, out);
}

// Round 4
// 205.360 us; speedup vs baseline: 1.3247x; 1.3247x over previous
//
#include <hip/hip_runtime.h>
#include <math.h>

#define D_MODELc 1024
#define N_HEADSc 16
#define D_Kc     64
#define B_SZc    2
#define S_LENc   2048
#define NTOKc    (B_SZc * S_LENc)   // 4096

using half8  = __attribute__((ext_vector_type(8))) _Float16;
using half4  = __attribute__((ext_vector_type(4))) _Float16;
using fp16x2 = __attribute__((ext_vector_type(2))) __fp16;
using float4v = __attribute__((ext_vector_type(4))) float;

// ---------------------------------------------------------------------------
// Fused convert: z<4 -> weight fp32->fp16 transpose; z==4 -> x fp32->fp16.
// ---------------------------------------------------------------------------
__global__ __launch_bounds__(256) void cvt_all(
    const float* __restrict__ x,
    const float* __restrict__ W0, const float* __restrict__ W1,
    const float* __restrict__ W2, const float* __restrict__ W3,
    _Float16* __restrict__ wout, _Float16* __restrict__ xout)
{
    __shared__ float T[32][33];
    const int z = blockIdx.z;
    const int t = threadIdx.x;

    if (z == 4) {   // x convert: 1024 virtual blocks x 512 half8
        const int bid = blockIdx.y * 32 + blockIdx.x;
        #pragma unroll
        for (int c = 0; c < 2; ++c) {
            const int i = bid * 512 + c * 256 + t;
            float4v a = ((const float4v*)x)[2 * i];
            float4v b = ((const float4v*)x)[2 * i + 1];
            half8 h;
            h[0] = (_Float16)a[0]; h[1] = (_Float16)a[1];
            h[2] = (_Float16)a[2]; h[3] = (_Float16)a[3];
            h[4] = (_Float16)b[0]; h[5] = (_Float16)b[1];
            h[6] = (_Float16)b[2]; h[7] = (_Float16)b[3];
            ((half8*)xout)[i] = h;
        }
        return;
    }

    const float* W = (z == 0) ? W0 : (z == 1) ? W1 : (z == 2) ? W2 : W3;
    _Float16* O = wout + (size_t)z * 1024 * 1024;

    const int k0 = blockIdx.x * 32;
    const int n0 = blockIdx.y * 32;
    {
        const int r = t >> 3, c4 = (t & 7) * 4;
        float4v v = *(const float4v*)(W + (size_t)(k0 + r) * 1024 + n0 + c4);
        T[r][c4 + 0] = v[0]; T[r][c4 + 1] = v[1];
        T[r][c4 + 2] = v[2]; T[r][c4 + 3] = v[3];
    }
    __syncthreads();
    {
        const int rn = t >> 3, ck4 = (t & 7) * 4;
        half4 h;
        h[0] = (_Float16)T[ck4 + 0][rn];
        h[1] = (_Float16)T[ck4 + 1][rn];
        h[2] = (_Float16)T[ck4 + 2][rn];
        h[3] = (_Float16)T[ck4 + 3][rn];
        *(half4*)(O + (size_t)(n0 + rn) * 1024 + k0 + ck4) = h;
    }
}

// ---------------------------------------------------------------------------
// QKV fp16 MFMA GEMM: 128x128 tiles, BK=64 via dual 32-k buffers.
// fp16 out, z-indexed: z==0 Q scaled by 0.125/ln2; z==1 K; z==2 V transposed.
// ---------------------------------------------------------------------------
__global__ __launch_bounds__(256) void gemm_qkv(
    const _Float16* __restrict__ A, const _Float16* __restrict__ BtAll,
    const float* __restrict__ bias0, const float* __restrict__ bias1,
    const float* __restrict__ bias2, _Float16* __restrict__ Cout)
{
    __shared__ _Float16 Als[2][128 * 32];
    __shared__ _Float16 Bls[2][128 * 32];

    constexpr int K = 1024;
    const int tid = threadIdx.x;
    const int m0  = blockIdx.x * 128;
    const int n0  = blockIdx.y * 128;
    const int z   = blockIdx.z;

    const _Float16* Bt  = BtAll + (size_t)z * 1024 * 1024;
    const float* bias   = (z == 0) ? bias0 : (z == 1) ? bias1 : bias2;
    const float qscale  = (z == 0) ? 0.18033688011112042f : 1.0f;

    const int wave = tid >> 6, lane = tid & 63;
    const int wr = wave >> 1, wc = wave & 1;
    const int quad = lane >> 4, l16 = lane & 15;

    float4v acc[4][4];
    #pragma unroll
    for (int i = 0; i < 4; ++i)
        #pragma unroll
        for (int j = 0; j < 4; ++j)
            acc[i][j] = (float4v){0.f, 0.f, 0.f, 0.f};

    for (int k0 = 0; k0 < K; k0 += 64) {
        #pragma unroll
        for (int c = 0; c < 2; ++c) {
            const int i   = c * 256 + tid;
            const int row = i >> 2, kc = i & 3;
            #pragma unroll
            for (int h = 0; h < 2; ++h) {
                __builtin_amdgcn_global_load_lds(
                    (const __attribute__((address_space(1))) void*)
                        (A + (size_t)(m0 + row) * K + k0 + h * 32 + kc * 8),
                    (__attribute__((address_space(3))) void*)(Als[h] + i * 8),
                    16, 0, 0);
                __builtin_amdgcn_global_load_lds(
                    (const __attribute__((address_space(1))) void*)
                        (Bt + (size_t)(n0 + row) * K + k0 + h * 32 + kc * 8),
                    (__attribute__((address_space(3))) void*)(Bls[h] + i * 8),
                    16, 0, 0);
            }
        }
        __syncthreads();

        half8 af[4][2], bf[4][2];
        #pragma unroll
        for (int i = 0; i < 4; ++i) {
            const int r = (wr * 64 + i * 16 + l16) * 32 + quad * 8;
            af[i][0] = *(const half8*)(Als[0] + r);
            af[i][1] = *(const half8*)(Als[1] + r);
        }
        #pragma unroll
        for (int j = 0; j < 4; ++j) {
            const int r = (wc * 64 + j * 16 + l16) * 32 + quad * 8;
            bf[j][0] = *(const half8*)(Bls[0] + r);
            bf[j][1] = *(const half8*)(Bls[1] + r);
        }
        #pragma unroll
        for (int i = 0; i < 4; ++i)
            #pragma unroll
            for (int j = 0; j < 4; ++j) {
                acc[i][j] = __builtin_amdgcn_mfma_f32_16x16x32_f16(
                    af[i][0], bf[j][0], acc[i][j], 0, 0, 0);
                acc[i][j] = __builtin_amdgcn_mfma_f32_16x16x32_f16(
                    af[i][1], bf[j][1], acc[i][j], 0, 0, 0);
            }
        __syncthreads();
    }

    if (z != 2) {
        // Q/K: [b,h,s,dk] scatter (fp16)
        #pragma unroll
        for (int i = 0; i < 4; ++i) {
            const int rbase = m0 + wr * 64 + i * 16 + quad * 4;
            #pragma unroll
            for (int j = 0; j < 4; ++j) {
                const int col = n0 + wc * 64 + j * 16 + l16;
                const float bv = bias[col];
                #pragma unroll
                for (int r = 0; r < 4; ++r) {
                    const float v = (acc[i][j][r] + bv) * qscale;
                    const int n = rbase + r;
                    const int b = n >> 11, s = n & 2047;
                    const int h = col >> 6, d = col & 63;
                    _Float16* C = Cout + (size_t)z * NTOKc * D_MODELc;
                    C[(((size_t)(b * N_HEADSc + h)) * S_LENc + s) * D_Kc + d] =
                        (_Float16)v;
                }
            }
        }
    } else {
        // V: [b,h,dk,s], half4 packed along tokens
        #pragma unroll
        for (int i = 0; i < 4; ++i) {
            const int rbase = m0 + wr * 64 + i * 16 + quad * 4;
            const int b = rbase >> 11, s0 = rbase & 2047;
            #pragma unroll
            for (int j = 0; j < 4; ++j) {
                const int col = n0 + wc * 64 + j * 16 + l16;
                const float bv = bias[col];
                const int h = col >> 6, d = col & 63;
                half4 hv;
                #pragma unroll
                for (int r = 0; r < 4; ++r)
                    hv[r] = (_Float16)(acc[i][j][r] + bv);
                _Float16* C = Cout + (size_t)2 * NTOKc * D_MODELc;
                *(half4*)(C + (((size_t)(b * N_HEADSc + h)) * D_Kc + d) *
                          S_LENc + s0) = hv;
            }
        }
    }
}

// ---------------------------------------------------------------------------
// Out-projection GEMM: C[4096,1024] fp32 = A @ Bt^T + bias.
// ---------------------------------------------------------------------------
__global__ __launch_bounds__(256) void gemm_out(
    const _Float16* __restrict__ A, const _Float16* __restrict__ Bt,
    const float* __restrict__ bias, float* __restrict__ C)
{
    __shared__ _Float16 Als[2][64 * 32];
    __shared__ _Float16 Bls[2][128 * 32];

    constexpr int K = 1024;
    const int tid = threadIdx.x;
    const int m0  = blockIdx.x * 64;
    const int n0  = blockIdx.y * 128;

    const int wave = tid >> 6, lane = tid & 63;
    const int wr = wave >> 1, wc = wave & 1;
    const int quad = lane >> 4, l16 = lane & 15;

    float4v acc[2][4];
    #pragma unroll
    for (int i = 0; i < 2; ++i)
        #pragma unroll
        for (int j = 0; j < 4; ++j)
            acc[i][j] = (float4v){0.f, 0.f, 0.f, 0.f};

    for (int k0 = 0; k0 < K; k0 += 64) {
        {   // A: 64 rows x 32 k per buffer
            const int row = tid >> 2, kc = tid & 3;
            #pragma unroll
            for (int h = 0; h < 2; ++h)
                __builtin_amdgcn_global_load_lds(
                    (const __attribute__((address_space(1))) void*)
                        (A + (size_t)(m0 + row) * K + k0 + h * 32 + kc * 8),
                    (__attribute__((address_space(3))) void*)(Als[h] + tid * 8),
                    16, 0, 0);
        }
        #pragma unroll
        for (int c = 0; c < 2; ++c) {   // B: 128 rows x 32 k per buffer
            const int i = c * 256 + tid;
            const int row = i >> 2, kc = i & 3;
            #pragma unroll
            for (int h = 0; h < 2; ++h)
                __builtin_amdgcn_global_load_lds(
                    (const __attribute__((address_space(1))) void*)
                        (Bt + (size_t)(n0 + row) * K + k0 + h * 32 + kc * 8),
                    (__attribute__((address_space(3))) void*)(Bls[h] + i * 8),
                    16, 0, 0);
        }
        __syncthreads();

        half8 af[2][2], bf[4][2];
        #pragma unroll
        for (int i = 0; i < 2; ++i) {
            const int r = (wr * 32 + i * 16 + l16) * 32 + quad * 8;
            af[i][0] = *(const half8*)(Als[0] + r);
            af[i][1] = *(const half8*)(Als[1] + r);
        }
        #pragma unroll
        for (int j = 0; j < 4; ++j) {
            const int r = (wc * 64 + j * 16 + l16) * 32 + quad * 8;
            bf[j][0] = *(const half8*)(Bls[0] + r);
            bf[j][1] = *(const half8*)(Bls[1] + r);
        }
        #pragma unroll
        for (int i = 0; i < 2; ++i)
            #pragma unroll
            for (int j = 0; j < 4; ++j) {
                acc[i][j] = __builtin_amdgcn_mfma_f32_16x16x32_f16(
                    af[i][0], bf[j][0], acc[i][j], 0, 0, 0);
                acc[i][j] = __builtin_amdgcn_mfma_f32_16x16x32_f16(
                    af[i][1], bf[j][1], acc[i][j], 0, 0, 0);
            }
        __syncthreads();
    }

    #pragma unroll
    for (int i = 0; i < 2; ++i) {
        const int rbase = m0 + wr * 32 + i * 16 + quad * 4;
        #pragma unroll
        for (int j = 0; j < 4; ++j) {
            const int col = n0 + wc * 64 + j * 16 + l16;
            const float bv = bias[col];
            #pragma unroll
            for (int r = 0; r < 4; ++r)
                C[(size_t)(rbase + r) * 1024 + col] = acc[i][j][r] + bv;
        }
    }
}

// ---------------------------------------------------------------------------
// MFMA flash attention, S^T form, NO-MAX softmax, SPLIT-K over keys (SP=2).
// R11: back to LDS staging (R10 proved it load-bearing: direct-global was
// VMEM-latency-bound, 129us), but via ASYNC global_load_lds (no data VGPRs,
// no ds_write VALU — avoids R8's register cost) with phase-split issue:
//   BAR1 -> stage V(t)   [latency hidden under QK phase]
//   BAR2 -> stage K(t+1) [latency hidden under PV phase; K double-buffered]
// Each barrier's vmcnt(0) drain finds its loads already landed (T3-minimal).
// global_load_lds forbids padding, so pad-72 is replaced by a ROW-ROTATION
// swizzle rot(row)=8*(row&7) whose read-side term depends only on the lane
// (row&7 == l16&7 for every fragment read) -> all LDS addrs lane-constant
// + compile-time offsets (what R8's XOR broke), conflict-free-uniform banks.
// Staging applies the inverse rotation on the GLOBAL source address (m173).
// LDS = 16KB K-dbuf + 8KB V + 16KB Ps = 40960B -> 4 blocks/CU kept.
// ---------------------------------------------------------------------------
__global__ __launch_bounds__(256) void attn_mfma(
    const _Float16* __restrict__ Qb, const _Float16* __restrict__ Kb,
    const _Float16* __restrict__ Vtg, _Float16* __restrict__ Op,
    float* __restrict__ Lp)
{
    __shared__ _Float16 Ks[2][64 * 64];    // K-tile [key][dk], rotated
    __shared__ _Float16 Vt[64 * 64];       // V-tile [dk][key], rotated
    __shared__ _Float16 Ps[128 * 64];      // P [qrow][key], rotated

    const int tid  = threadIdx.x;
    const int wv   = tid >> 6;
    const int lane = tid & 63;
    const int quad = lane >> 4;
    const int l16  = lane & 15;
    const int rotl = (l16 & 7) << 3;       // read-side rotation (halves)
    const int cA   = (quad * 8 + rotl) & 63;        // frag col, lo half
    const int cB   = (quad * 8 + 32 + rotl) & 63;   // frag col, hi half

    const int q0 = blockIdx.x * 128;
    const int bh = blockIdx.y;
    const int sp = blockIdx.z;             // key split
    const int kb = sp * (S_LENc / 2);
    const int kend = kb + S_LENc / 2;

    const _Float16* Qsl = Qb  + (size_t)bh * S_LENc * D_Kc;
    const _Float16* Ksl = Kb  + (size_t)bh * S_LENc * D_Kc;
    const _Float16* Vsl = Vtg + (size_t)bh * S_LENc * D_Kc;   // [dk][s]

    // staging geometry: 512 chunks x 8 halves; chunk idx = c*256+tid.
    // LDS dest (linear, lane-contiguous): idx*8.  dest row r=idx>>3,
    // dest col c'=(idx&7)*8; source col = (c' - 8*(r&7)) & 63 (inverse rot).
    const int sR = tid >> 3;                       // row for c=0 (c=1: +32)
    const int sC = (((tid & 7) - ((tid >> 3) & 7)) & 7) << 3;
    const _Float16* gK = Ksl + (size_t)sR * 64 + sC;       // + t0*64 + c*2048
    const _Float16* gV = Vsl + (size_t)sR * S_LENc + sC;   // + t0 + c*65536

#define STAGE_KT(BUF, T0)                                                    \
    {                                                                        \
        _Pragma("unroll")                                                    \
        for (int c = 0; c < 2; ++c)                                          \
            __builtin_amdgcn_global_load_lds(                                \
                (const __attribute__((address_space(1))) void*)              \
                    (gK + (size_t)(T0) * 64 + c * 2048),                     \
                (__attribute__((address_space(3))) void*)                    \
                    (Ks[BUF] + tid * 8 + c * 2048),                          \
                16, 0, 0);                                                   \
    }
#define STAGE_VT(T0)                                                         \
    {                                                                        \
        _Pragma("unroll")                                                    \
        for (int c = 0; c < 2; ++c)                                          \
            __builtin_amdgcn_global_load_lds(                                \
                (const __attribute__((address_space(1))) void*)              \
                    (gV + (T0) + c * 32 * S_LENc),                           \
                (__attribute__((address_space(3))) void*)                    \
                    (Vt + tid * 8 + c * 2048),                               \
                16, 0, 0);                                                   \
    }

    // Q B-operand frags: lane l16 = qrow
    half8 aq[2][2];
    #pragma unroll
    for (int qf = 0; qf < 2; ++qf) {
        const int row = q0 + wv * 32 + qf * 16 + l16;
        aq[qf][0] = *(const half8*)(Qsl + (size_t)row * 64 + quad * 8);
        aq[qf][1] = *(const half8*)(Qsl + (size_t)row * 64 + 32 + quad * 8);
    }

    float4v O[2][4];                   // [qf][dk-tile]
    #pragma unroll
    for (int qf = 0; qf < 2; ++qf)
        #pragma unroll
        for (int nt = 0; nt < 4; ++nt)
            O[qf][nt] = (float4v){0.f, 0.f, 0.f, 0.f};
    float lr[2] = {0.f, 0.f};          // per-lane partial sum

    // prologue: stage first K and V tiles
    STAGE_KT(0, kb);
    STAGE_VT(kb);

    int cur = 0;
    for (int t0 = kb; t0 < kend; t0 += 64) {
        __syncthreads();               // BAR1: K[cur]+V(t0) landed; PV(prev) done
        if (t0 != kb)
            STAGE_VT(t0);              // overwrite V — all waves past PV(prev)

        // ---- QK phase (hides V(t0) latency; for t0==kb V came in prologue)
        const _Float16* KsC = Ks[cur];
        half8 kf[4][2];
        #pragma unroll
        for (int nt = 0; nt < 4; ++nt) {
            const int base = (nt * 16 + l16) * 64;
            kf[nt][0] = *(const half8*)(KsC + base + cA);
            kf[nt][1] = *(const half8*)(KsC + base + cB);
        }

        #pragma unroll
        for (int qf = 0; qf < 2; ++qf) {
            float4v st[4];
            __builtin_amdgcn_s_setprio(1);
            #pragma unroll
            for (int nt = 0; nt < 4; ++nt) {
                st[nt] = __builtin_amdgcn_mfma_f32_16x16x32_f16(
                    kf[nt][0], aq[qf][0], (float4v){0.f, 0.f, 0.f, 0.f}, 0, 0, 0);
                st[nt] = __builtin_amdgcn_mfma_f32_16x16x32_f16(
                    kf[nt][1], aq[qf][1], st[nt], 0, 0, 0);
            }
            __builtin_amdgcn_s_setprio(0);
            float ls = 0.f;
            const int rowP = (wv * 32 + qf * 16 + l16) * 64;
            #pragma unroll
            for (int nt = 0; nt < 4; ++nt) {
                const float p0 = __builtin_amdgcn_exp2f(fminf(st[nt][0], 15.5f));
                const float p1 = __builtin_amdgcn_exp2f(fminf(st[nt][1], 15.5f));
                const float p2 = __builtin_amdgcn_exp2f(fminf(st[nt][2], 15.5f));
                const float p3 = __builtin_amdgcn_exp2f(fminf(st[nt][3], 15.5f));
                ls += (p0 + p1) + (p2 + p3);
                union { fp16x2 h2[2]; half4 h4; } u;
                u.h2[0] = __builtin_amdgcn_cvt_pkrtz(p0, p1);
                u.h2[1] = __builtin_amdgcn_cvt_pkrtz(p2, p3);
                *(half4*)(Ps + rowP + ((nt * 16 + quad * 4 + rotl) & 63)) = u.h4;
            }
            lr[qf] += ls;
        }

        __syncthreads();               // BAR2: V(t0) visible to all waves
        if (t0 + 64 < kend)
            STAGE_KT(cur ^ 1, t0 + 64);  // hides under PV phase

        // ---- PV phase
        half8 bvv[4][2];
        #pragma unroll
        for (int nt = 0; nt < 4; ++nt) {
            const int base = (nt * 16 + l16) * 64;
            bvv[nt][0] = *(const half8*)(Vt + base + cA);
            bvv[nt][1] = *(const half8*)(Vt + base + cB);
        }
        #pragma unroll
        for (int qf = 0; qf < 2; ++qf) {
            const int rowP = (wv * 32 + qf * 16 + l16) * 64;
            half8 ap0 = *(const half8*)(Ps + rowP + cA);
            half8 ap1 = *(const half8*)(Ps + rowP + cB);
            __builtin_amdgcn_s_setprio(1);
            #pragma unroll
            for (int nt = 0; nt < 4; ++nt) {
                O[qf][nt] = __builtin_amdgcn_mfma_f32_16x16x32_f16(
                    ap0, bvv[nt][0], O[qf][nt], 0, 0, 0);
                O[qf][nt] = __builtin_amdgcn_mfma_f32_16x16x32_f16(
                    ap1, bvv[nt][1], O[qf][nt], 0, 0, 0);
            }
            __builtin_amdgcn_s_setprio(0);
        }
        cur ^= 1;
    }
#undef STAGE_KT
#undef STAGE_VT

    // epilogue: write unnormalized partials
    const size_t qgb = (size_t)bh * S_LENc;
    #pragma unroll
    for (int qf = 0; qf < 2; ++qf) {
        float t = lr[qf];
        t += __shfl_xor(t, 16, 64);
        t += __shfl_xor(t, 32, 64);
        if (quad == 0)
            Lp[(size_t)sp * 65536 + qgb + q0 + wv * 32 + qf * 16 + l16] = t;
        #pragma unroll
        for (int r = 0; r < 4; ++r) {
            const int q = q0 + wv * 32 + qf * 16 + quad * 4 + r;
            _Float16* dst = Op + ((size_t)sp * 65536 + qgb + q) * 64;
            #pragma unroll
            for (int nt = 0; nt < 4; ++nt)
                dst[nt * 16 + l16] = (_Float16)O[qf][nt][r];
        }
    }
}

// ---------------------------------------------------------------------------
// Combine split-K partials: Ah[b][s][h*64+d] = (O0+O1) / (l0+l1).
// ---------------------------------------------------------------------------
__global__ __launch_bounds__(256) void attn_combine(
    const _Float16* __restrict__ Op, const float* __restrict__ Lp,
    _Float16* __restrict__ Ab)
{
    const int i  = blockIdx.x * 256 + threadIdx.x;
    const int e0 = i * 8;
    const int qg = e0 >> 6;            // bh*2048 + q
    const int d0 = e0 & 63;
    const int bh = qg >> 11, q = qg & 2047;
    const int b  = bh >> 4,  h = bh & 15;

    const float inv = 1.0f / (Lp[qg] + Lp[65536 + qg]);
    half8 o0 = *(const half8*)(Op + (size_t)qg * 64 + d0);
    half8 o1 = *(const half8*)(Op + ((size_t)65536 + qg) * 64 + d0);
    half8 hv;
    #pragma unroll
    for (int j = 0; j < 8; ++j)
        hv[j] = (_Float16)(((float)o0[j] + (float)o1[j]) * inv);
    *(half8*)(Ab + ((size_t)(b * S_LENc + q)) * 1024 + h * 64 + d0) = hv;
}

// ---------------------------------------------------------------------------
extern "C" void kernel_launch(void* const* d_in, const int* in_sizes, int n_in,
                              void* d_out, int out_size, void* d_ws, size_t ws_size,
                              hipStream_t stream)
{
    const float* x  = (const float*)d_in[0];
    const float* wq = (const float*)d_in[1];
    const float* bq = (const float*)d_in[2];
    const float* wk = (const float*)d_in[3];
    const float* bk = (const float*)d_in[4];
    const float* wv = (const float*)d_in[5];
    const float* bv = (const float*)d_in[6];
    const float* wo = (const float*)d_in[7];
    const float* bo = (const float*)d_in[8];
    float* out = (float*)d_out;

    const size_t M1 = 1024 * 1024;
    const size_t M4 = 4 * M1;                 // 4.19M elements
    _Float16* xh = (_Float16*)d_ws;           // [0, 8.4MB)  also reused as Ah
    _Float16* wh = xh + M4;                   // 4 x 1M halves
    _Float16* Qh = wh + M4;                   // Q,K,V: 3 x 4M halves
    _Float16* Oph = Qh + 3 * M4;              // split partials: 2 x 4M halves
    float*    Lp  = (float*)(Oph + 2 * M4);   // 2 x 65536 floats
    _Float16* Ah = xh;                        // xh dead after QKV gemm

    cvt_all<<<dim3(32, 32, 5), dim3(256), 0, stream>>>(
        x, wq, wk, wv, wo, wh, xh);
    gemm_qkv<<<dim3(NTOKc / 128, D_MODELc / 128, 3), dim3(256), 0, stream>>>(
        xh, wh, bq, bk, bv, Qh);
    attn_mfma<<<dim3(S_LENc / 128, B_SZc * N_HEADSc, 2), dim3(256), 0, stream>>>(
        Qh, Qh + M4, Qh + 2 * M4, Oph, Lp);
    attn_combine<<<dim3(NTOKc * D_MODELc / 8 / 256), dim3(256), 0, stream>>>(
        Oph, Lp, Ah);
    gemm_out<<<dim3(NTOKc / 64, D_MODELc / 128), dim3(256), 0, stream>>>(
        Ah, wh + 3 * M1, bo, out);
}

// Round 6
// 204.321 us; speedup vs baseline: 1.3315x; 1.0051x over previous
//
#include <hip/hip_runtime.h>
#include <math.h>

#define D_MODELc 1024
#define N_HEADSc 16
#define D_Kc     64
#define B_SZc    2
#define S_LENc   2048
#define NTOKc    (B_SZc * S_LENc)   // 4096

using half8  = __attribute__((ext_vector_type(8))) _Float16;
using half4  = __attribute__((ext_vector_type(4))) _Float16;
using fp16x2 = __attribute__((ext_vector_type(2))) __fp16;
using float4v = __attribute__((ext_vector_type(4))) float;

// ---------------------------------------------------------------------------
// Fused convert: z<4 -> weight fp32->fp16 transpose; z==4 -> x fp32->fp16.
// ---------------------------------------------------------------------------
__global__ __launch_bounds__(256) void cvt_all(
    const float* __restrict__ x,
    const float* __restrict__ W0, const float* __restrict__ W1,
    const float* __restrict__ W2, const float* __restrict__ W3,
    _Float16* __restrict__ wout, _Float16* __restrict__ xout)
{
    __shared__ float T[32][33];
    const int z = blockIdx.z;
    const int t = threadIdx.x;

    if (z == 4) {   // x convert: 1024 virtual blocks x 512 half8
        const int bid = blockIdx.y * 32 + blockIdx.x;
        #pragma unroll
        for (int c = 0; c < 2; ++c) {
            const int i = bid * 512 + c * 256 + t;
            float4v a = ((const float4v*)x)[2 * i];
            float4v b = ((const float4v*)x)[2 * i + 1];
            half8 h;
            h[0] = (_Float16)a[0]; h[1] = (_Float16)a[1];
            h[2] = (_Float16)a[2]; h[3] = (_Float16)a[3];
            h[4] = (_Float16)b[0]; h[5] = (_Float16)b[1];
            h[6] = (_Float16)b[2]; h[7] = (_Float16)b[3];
            ((half8*)xout)[i] = h;
        }
        return;
    }

    const float* W = (z == 0) ? W0 : (z == 1) ? W1 : (z == 2) ? W2 : W3;
    _Float16* O = wout + (size_t)z * 1024 * 1024;

    const int k0 = blockIdx.x * 32;
    const int n0 = blockIdx.y * 32;
    {
        const int r = t >> 3, c4 = (t & 7) * 4;
        float4v v = *(const float4v*)(W + (size_t)(k0 + r) * 1024 + n0 + c4);
        T[r][c4 + 0] = v[0]; T[r][c4 + 1] = v[1];
        T[r][c4 + 2] = v[2]; T[r][c4 + 3] = v[3];
    }
    __syncthreads();
    {
        const int rn = t >> 3, ck4 = (t & 7) * 4;
        half4 h;
        h[0] = (_Float16)T[ck4 + 0][rn];
        h[1] = (_Float16)T[ck4 + 1][rn];
        h[2] = (_Float16)T[ck4 + 2][rn];
        h[3] = (_Float16)T[ck4 + 3][rn];
        *(half4*)(O + (size_t)(n0 + rn) * 1024 + k0 + ck4) = h;
    }
}

// ---------------------------------------------------------------------------
// QKV fp16 MFMA GEMM: 128x128 tiles, BK=64 via dual 32-k buffers.
// Q/K written TOKEN-MAJOR [tok][h*64+d]; z==0 Q scaled by 0.125/ln2;
// z==2 V TRANSPOSED [b,h,dk,s] (half4 stores).
// ---------------------------------------------------------------------------
__global__ __launch_bounds__(256) void gemm_qkv(
    const _Float16* __restrict__ A, const _Float16* __restrict__ BtAll,
    const float* __restrict__ bias0, const float* __restrict__ bias1,
    const float* __restrict__ bias2, _Float16* __restrict__ Cout)
{
    __shared__ _Float16 Als[2][128 * 32];
    __shared__ _Float16 Bls[2][128 * 32];

    constexpr int K = 1024;
    const int tid = threadIdx.x;
    const int m0  = blockIdx.x * 128;
    const int n0  = blockIdx.y * 128;
    const int z   = blockIdx.z;

    const _Float16* Bt  = BtAll + (size_t)z * 1024 * 1024;
    const float* bias   = (z == 0) ? bias0 : (z == 1) ? bias1 : bias2;
    const float qscale  = (z == 0) ? 0.18033688011112042f : 1.0f;

    const int wave = tid >> 6, lane = tid & 63;
    const int wr = wave >> 1, wc = wave & 1;
    const int quad = lane >> 4, l16 = lane & 15;

    float4v acc[4][4];
    #pragma unroll
    for (int i = 0; i < 4; ++i)
        #pragma unroll
        for (int j = 0; j < 4; ++j)
            acc[i][j] = (float4v){0.f, 0.f, 0.f, 0.f};

    for (int k0 = 0; k0 < K; k0 += 64) {
        #pragma unroll
        for (int c = 0; c < 2; ++c) {
            const int i   = c * 256 + tid;
            const int row = i >> 2, kc = i & 3;
            #pragma unroll
            for (int h = 0; h < 2; ++h) {
                __builtin_amdgcn_global_load_lds(
                    (const __attribute__((address_space(1))) void*)
                        (A + (size_t)(m0 + row) * K + k0 + h * 32 + kc * 8),
                    (__attribute__((address_space(3))) void*)(Als[h] + i * 8),
                    16, 0, 0);
                __builtin_amdgcn_global_load_lds(
                    (const __attribute__((address_space(1))) void*)
                        (Bt + (size_t)(n0 + row) * K + k0 + h * 32 + kc * 8),
                    (__attribute__((address_space(3))) void*)(Bls[h] + i * 8),
                    16, 0, 0);
            }
        }
        __syncthreads();

        half8 af[4][2], bf[4][2];
        #pragma unroll
        for (int i = 0; i < 4; ++i) {
            const int r = (wr * 64 + i * 16 + l16) * 32 + quad * 8;
            af[i][0] = *(const half8*)(Als[0] + r);
            af[i][1] = *(const half8*)(Als[1] + r);
        }
        #pragma unroll
        for (int j = 0; j < 4; ++j) {
            const int r = (wc * 64 + j * 16 + l16) * 32 + quad * 8;
            bf[j][0] = *(const half8*)(Bls[0] + r);
            bf[j][1] = *(const half8*)(Bls[1] + r);
        }
        #pragma unroll
        for (int i = 0; i < 4; ++i)
            #pragma unroll
            for (int j = 0; j < 4; ++j) {
                acc[i][j] = __builtin_amdgcn_mfma_f32_16x16x32_f16(
                    af[i][0], bf[j][0], acc[i][j], 0, 0, 0);
                acc[i][j] = __builtin_amdgcn_mfma_f32_16x16x32_f16(
                    af[i][1], bf[j][1], acc[i][j], 0, 0, 0);
            }
        __syncthreads();
    }

    if (z != 2) {
        // Q/K: token-major [tok][h*64+d] — natural coalesced stores
        _Float16* C = Cout + (size_t)z * NTOKc * D_MODELc;
        #pragma unroll
        for (int i = 0; i < 4; ++i) {
            const int rbase = m0 + wr * 64 + i * 16 + quad * 4;
            #pragma unroll
            for (int j = 0; j < 4; ++j) {
                const int col = n0 + wc * 64 + j * 16 + l16;
                const float bv = bias[col];
                #pragma unroll
                for (int r = 0; r < 4; ++r)
                    C[(size_t)(rbase + r) * 1024 + col] =
                        (_Float16)((acc[i][j][r] + bv) * qscale);
            }
        }
    } else {
        // V: [b,h,dk,s], half4 packed along tokens
        #pragma unroll
        for (int i = 0; i < 4; ++i) {
            const int rbase = m0 + wr * 64 + i * 16 + quad * 4;
            const int b = rbase >> 11, s0 = rbase & 2047;
            #pragma unroll
            for (int j = 0; j < 4; ++j) {
                const int col = n0 + wc * 64 + j * 16 + l16;
                const float bv = bias[col];
                const int h = col >> 6, d = col & 63;
                half4 hv;
                #pragma unroll
                for (int r = 0; r < 4; ++r)
                    hv[r] = (_Float16)(acc[i][j][r] + bv);
                _Float16* C = Cout + (size_t)2 * NTOKc * D_MODELc;
                *(half4*)(C + (((size_t)(b * N_HEADSc + h)) * D_Kc + d) *
                          S_LENc + s0) = hv;
            }
        }
    }
}

// ---------------------------------------------------------------------------
// Out-projection GEMM: C[4096,1024] fp32 = A @ Bt^T + bias.
// ---------------------------------------------------------------------------
__global__ __launch_bounds__(256) void gemm_out(
    const _Float16* __restrict__ A, const _Float16* __restrict__ Bt,
    const float* __restrict__ bias, float* __restrict__ C)
{
    __shared__ _Float16 Als[2][64 * 32];
    __shared__ _Float16 Bls[2][128 * 32];

    constexpr int K = 1024;
    const int tid = threadIdx.x;
    const int m0  = blockIdx.x * 64;
    const int n0  = blockIdx.y * 128;

    const int wave = tid >> 6, lane = tid & 63;
    const int wr = wave >> 1, wc = wave & 1;
    const int quad = lane >> 4, l16 = lane & 15;

    float4v acc[2][4];
    #pragma unroll
    for (int i = 0; i < 2; ++i)
        #pragma unroll
        for (int j = 0; j < 4; ++j)
            acc[i][j] = (float4v){0.f, 0.f, 0.f, 0.f};

    for (int k0 = 0; k0 < K; k0 += 64) {
        {   // A: 64 rows x 32 k per buffer
            const int row = tid >> 2, kc = tid & 3;
            #pragma unroll
            for (int h = 0; h < 2; ++h)
                __builtin_amdgcn_global_load_lds(
                    (const __attribute__((address_space(1))) void*)
                        (A + (size_t)(m0 + row) * K + k0 + h * 32 + kc * 8),
                    (__attribute__((address_space(3))) void*)(Als[h] + tid * 8),
                    16, 0, 0);
        }
        #pragma unroll
        for (int c = 0; c < 2; ++c) {   // B: 128 rows x 32 k per buffer
            const int i = c * 256 + tid;
            const int row = i >> 2, kc = i & 3;
            #pragma unroll
            for (int h = 0; h < 2; ++h)
                __builtin_amdgcn_global_load_lds(
                    (const __attribute__((address_space(1))) void*)
                        (Bt + (size_t)(n0 + row) * K + k0 + h * 32 + kc * 8),
                    (__attribute__((address_space(3))) void*)(Bls[h] + i * 8),
                    16, 0, 0);
        }
        __syncthreads();

        half8 af[2][2], bf[4][2];
        #pragma unroll
        for (int i = 0; i < 2; ++i) {
            const int r = (wr * 32 + i * 16 + l16) * 32 + quad * 8;
            af[i][0] = *(const half8*)(Als[0] + r);
            af[i][1] = *(const half8*)(Als[1] + r);
        }
        #pragma unroll
        for (int j = 0; j < 4; ++j) {
            const int r = (wc * 64 + j * 16 + l16) * 32 + quad * 8;
            bf[j][0] = *(const half8*)(Bls[0] + r);
            bf[j][1] = *(const half8*)(Bls[1] + r);
        }
        #pragma unroll
        for (int i = 0; i < 2; ++i)
            #pragma unroll
            for (int j = 0; j < 4; ++j) {
                acc[i][j] = __builtin_amdgcn_mfma_f32_16x16x32_f16(
                    af[i][0], bf[j][0], acc[i][j], 0, 0, 0);
                acc[i][j] = __builtin_amdgcn_mfma_f32_16x16x32_f16(
                    af[i][1], bf[j][1], acc[i][j], 0, 0, 0);
            }
        __syncthreads();
    }

    #pragma unroll
    for (int i = 0; i < 2; ++i) {
        const int rbase = m0 + wr * 32 + i * 16 + quad * 4;
        #pragma unroll
        for (int j = 0; j < 4; ++j) {
            const int col = n0 + wc * 64 + j * 16 + l16;
            const float bv = bias[col];
            #pragma unroll
            for (int r = 0; r < 4; ++r)
                C[(size_t)(rbase + r) * 1024 + col] = acc[i][j][r] + bv;
        }
    }
}

// ---------------------------------------------------------------------------
// MFMA flash attention, S^T form, NO-MAX softmax. R13:
// SCHEDULE = R11's harness-verified pattern, verbatim:
//   prologue: stage K(0)->buf0, stage V(0)
//   loop: BAR1 (drains K[cur],V staged earlier); if t0!=0 stage V(t0);
//         QK from Ks[cur]; BAR2 (drains V(t0); all K reads done);
//         stage K(t0+64)->Ks[cur^1]; PV; cur^=1
//   (R12's novel K-single/V-lead schedule failed at 6.7e-2 — reverted.)
// KEPT from R12 (all index-verified, layout-safe):
//   * ones-MFMA L row-sum: Lacc=mfma(ap,1s) on the MFMA pipe; Lacc C-layout
//     (row=quad*4+r) matches O -> shuffle-free in-kernel normalization.
//   * SP=1 + direct normalized write -> attn_combine kernel deleted.
//   * token-major Q/K [tok][h*64+d]; 64 q-rows/block (4 waves x 16 rows).
//   * R11 rotation swizzle (lane-constant read addrs; inverse rot on the
//     global source address).
// LDS = 16(K dbuf) + 8(V) + 8(Ps) = 32KB.
// ---------------------------------------------------------------------------
__global__ __launch_bounds__(256) void attn_mfma(
    const _Float16* __restrict__ Qt, const _Float16* __restrict__ Kt,
    const _Float16* __restrict__ Vtg, _Float16* __restrict__ Ab)
{
    __shared__ _Float16 Ks[2][64 * 64];    // K-tile [key][dk], rotated, dbuf
    __shared__ _Float16 Vt[64 * 64];       // V-tile [dk][key], rotated
    __shared__ _Float16 Ps[64 * 64];       // P [qrow][key], rotated

    const int tid  = threadIdx.x;
    const int wv   = tid >> 6;
    const int lane = tid & 63;
    const int quad = lane >> 4;
    const int l16  = lane & 15;
    const int rotl = (l16 & 7) << 3;
    const int cA   = (quad * 8 + rotl) & 63;
    const int cB   = (quad * 8 + 32 + rotl) & 63;

    const int q0 = blockIdx.x * 64;
    const int bh = blockIdx.y;
    const int b  = bh >> 4, h = bh & 15;

    const _Float16* Qsl = Qt + (size_t)b * S_LENc * D_MODELc + h * 64;
    const _Float16* Ksl = Kt + (size_t)b * S_LENc * D_MODELc + h * 64;
    const _Float16* Vsl = Vtg + (size_t)bh * S_LENc * D_Kc;   // [dk][s]

    const int sR = tid >> 3;
    const int sC = (((tid & 7) - ((tid >> 3) & 7)) & 7) << 3;
    const _Float16* gK = Ksl + (size_t)sR * D_MODELc + sC;
    const _Float16* gV = Vsl + (size_t)sR * S_LENc + sC;

#define STAGE_K(BUF, T0)                                                     \
    {                                                                        \
        _Pragma("unroll")                                                    \
        for (int c = 0; c < 2; ++c)                                          \
            __builtin_amdgcn_global_load_lds(                                \
                (const __attribute__((address_space(1))) void*)              \
                    (gK + (size_t)((T0) + c * 32) * D_MODELc),               \
                (__attribute__((address_space(3))) void*)                    \
                    (Ks[BUF] + tid * 8 + c * 2048),                          \
                16, 0, 0);                                                   \
    }
#define STAGE_V(T0)                                                          \
    {                                                                        \
        _Pragma("unroll")                                                    \
        for (int c = 0; c < 2; ++c)                                          \
            __builtin_amdgcn_global_load_lds(                                \
                (const __attribute__((address_space(1))) void*)              \
                    (gV + (T0) + c * 32 * S_LENc),                           \
                (__attribute__((address_space(3))) void*)                    \
                    (Vt + tid * 8 + c * 2048),                               \
                16, 0, 0);                                                   \
    }

    half8 aq[2];
    {
        const _Float16* qp = Qsl + (size_t)(q0 + wv * 16 + l16) * D_MODELc;
        aq[0] = *(const half8*)(qp + quad * 8);
        aq[1] = *(const half8*)(qp + 32 + quad * 8);
    }

    half8 vones;
    #pragma unroll
    for (int j = 0; j < 8; ++j) vones[j] = (_Float16)1.0f;

    float4v O[4];                      // qrow=quad*4+r, dk=nt*16+l16
    #pragma unroll
    for (int nt = 0; nt < 4; ++nt)
        O[nt] = (float4v){0.f, 0.f, 0.f, 0.f};
    float4v Lacc = (float4v){0.f, 0.f, 0.f, 0.f};   // L[qrow=quad*4+r]

    STAGE_K(0, 0);
    STAGE_V(0);

    int cur = 0;
    for (int t0 = 0; t0 < S_LENc; t0 += 64) {
        __syncthreads();               // BAR1: K[cur](t0) landed; PV(prev) done
        if (t0 != 0)
            STAGE_V(t0);               // V(t0): drained at BAR2, read in PV(t0)

        // ---- QK phase
        const _Float16* KsC = Ks[cur];
        half8 kf[4][2];
        #pragma unroll
        for (int nt = 0; nt < 4; ++nt) {
            const int base = (nt * 16 + l16) * 64;
            kf[nt][0] = *(const half8*)(KsC + base + cA);
            kf[nt][1] = *(const half8*)(KsC + base + cB);
        }

        float4v st[4];
        __builtin_amdgcn_s_setprio(1);
        #pragma unroll
        for (int nt = 0; nt < 4; ++nt) {
            st[nt] = __builtin_amdgcn_mfma_f32_16x16x32_f16(
                kf[nt][0], aq[0], (float4v){0.f, 0.f, 0.f, 0.f}, 0, 0, 0);
            st[nt] = __builtin_amdgcn_mfma_f32_16x16x32_f16(
                kf[nt][1], aq[1], st[nt], 0, 0, 0);
        }
        __builtin_amdgcn_s_setprio(0);

        const int rowP = (wv * 16 + l16) * 64;
        #pragma unroll
        for (int nt = 0; nt < 4; ++nt) {
            const float p0 = __builtin_amdgcn_exp2f(fminf(st[nt][0], 15.5f));
            const float p1 = __builtin_amdgcn_exp2f(fminf(st[nt][1], 15.5f));
            const float p2 = __builtin_amdgcn_exp2f(fminf(st[nt][2], 15.5f));
            const float p3 = __builtin_amdgcn_exp2f(fminf(st[nt][3], 15.5f));
            union { fp16x2 h2[2]; half4 h4; } u;
            u.h2[0] = __builtin_amdgcn_cvt_pkrtz(p0, p1);
            u.h2[1] = __builtin_amdgcn_cvt_pkrtz(p2, p3);
            *(half4*)(Ps + rowP + ((nt * 16 + quad * 4 + rotl) & 63)) = u.h4;
        }

        __syncthreads();               // BAR2: V(t0) landed; K[cur] reads done
        if (t0 + 64 < S_LENc)
            STAGE_K(cur ^ 1, t0 + 64); // hides under PV; lands by next BAR1

        // ---- PV phase (+ L row-sum on MFMA pipe)
        half8 bvv[4][2];
        #pragma unroll
        for (int nt = 0; nt < 4; ++nt) {
            const int base = (nt * 16 + l16) * 64;
            bvv[nt][0] = *(const half8*)(Vt + base + cA);
            bvv[nt][1] = *(const half8*)(Vt + base + cB);
        }
        half8 ap0 = *(const half8*)(Ps + rowP + cA);
        half8 ap1 = *(const half8*)(Ps + rowP + cB);
        __builtin_amdgcn_s_setprio(1);
        #pragma unroll
        for (int nt = 0; nt < 4; ++nt) {
            O[nt] = __builtin_amdgcn_mfma_f32_16x16x32_f16(
                ap0, bvv[nt][0], O[nt], 0, 0, 0);
            O[nt] = __builtin_amdgcn_mfma_f32_16x16x32_f16(
                ap1, bvv[nt][1], O[nt], 0, 0, 0);
        }
        Lacc = __builtin_amdgcn_mfma_f32_16x16x32_f16(ap0, vones, Lacc, 0, 0, 0);
        Lacc = __builtin_amdgcn_mfma_f32_16x16x32_f16(ap1, vones, Lacc, 0, 0, 0);
        __builtin_amdgcn_s_setprio(0);
        cur ^= 1;
    }
#undef STAGE_K
#undef STAGE_V

    // epilogue: normalize, write token-major [b,s,h*64+d]
    _Float16* Asl = Ab + (size_t)b * S_LENc * D_MODELc + h * 64;
    #pragma unroll
    for (int r = 0; r < 4; ++r) {
        const float inv = 1.0f / Lacc[r];
        const int q = q0 + wv * 16 + quad * 4 + r;
        _Float16* dst = Asl + (size_t)q * D_MODELc;
        #pragma unroll
        for (int nt = 0; nt < 4; ++nt)
            dst[nt * 16 + l16] = (_Float16)(O[nt][r] * inv);
    }
}

// ---------------------------------------------------------------------------
extern "C" void kernel_launch(void* const* d_in, const int* in_sizes, int n_in,
                              void* d_out, int out_size, void* d_ws, size_t ws_size,
                              hipStream_t stream)
{
    const float* x  = (const float*)d_in[0];
    const float* wq = (const float*)d_in[1];
    const float* bq = (const float*)d_in[2];
    const float* wk = (const float*)d_in[3];
    const float* bk = (const float*)d_in[4];
    const float* wv = (const float*)d_in[5];
    const float* bv = (const float*)d_in[6];
    const float* wo = (const float*)d_in[7];
    const float* bo = (const float*)d_in[8];
    float* out = (float*)d_out;

    const size_t M1 = 1024 * 1024;
    const size_t M4 = 4 * M1;                 // 4.19M elements
    _Float16* xh = (_Float16*)d_ws;           // [0, 8.4MB)  also reused as Ah
    _Float16* wh = xh + M4;                   // 4 x 1M halves
    _Float16* Qh = wh + M4;                   // Q,K,V: 3 x 4M halves
    _Float16* Ah = xh;                        // xh dead after QKV gemm

    cvt_all<<<dim3(32, 32, 5), dim3(256), 0, stream>>>(
        x, wq, wk, wv, wo, wh, xh);
    gemm_qkv<<<dim3(NTOKc / 128, D_MODELc / 128, 3), dim3(256), 0, stream>>>(
        xh, wh, bq, bk, bv, Qh);
    attn_mfma<<<dim3(S_LENc / 64, B_SZc * N_HEADSc), dim3(256), 0, stream>>>(
        Qh, Qh + M4, Qh + 2 * M4, Ah);
    gemm_out<<<dim3(NTOKc / 64, D_MODELc / 128), dim3(256), 0, stream>>>(
        Ah, wh + 3 * M1, bo, out);
}